// Round 1
// baseline (1119.052 us; speedup 1.0000x reference)
//
#include <hip/hip_runtime.h>

// Problem constants (from reference): F=4, B=16384, L=12, V=1e6, E=64
#define NF 4
#define NB 16384
#define NL 12
#define NV 1000000
#define NE 64

// One block = one batch element b. 4 waves = 4 features.
// Lane e (0..63) owns embedding element e -> coalesced 256B row loads.
__global__ __launch_bounds__(256) void bag_kernel(
    const float* __restrict__ tables,      // [F, V, E]
    const float* __restrict__ pos_weights, // [F, L]
    const int*   __restrict__ indices,     // [F, B, L]
    const int*   __restrict__ lengths,     // [F, B]
    float*       __restrict__ pred,        // [B, F*E]  (d_out + 1)
    float*       __restrict__ partial)     // [gridDim.x] block partial sums for loss
{
    const int tid  = threadIdx.x;
    const int lane = tid & 63;
    const int f    = tid >> 6;       // wave id == feature id
    const int b    = blockIdx.x;

    const int len = lengths[f * NB + b];
    const int nn  = len < NL ? len : NL;

    const int*   idxp = indices + ((size_t)f * NB + b) * NL;
    const float* pw   = pos_weights + f * NL;
    const float* tbl  = tables + (size_t)f * (size_t)NV * NE;

    // Read all indices (wave-uniform broadcast loads) and masked weights.
    int   idxv[NL];
    float w[NL];
#pragma unroll
    for (int l = 0; l < NL; ++l) {
        idxv[l] = idxp[l];
        w[l]    = (l < nn) ? pw[l] : 0.0f;
    }

    // Issue all row gathers up front for ILP; guard is wave-uniform.
    float vals[NL];
#pragma unroll
    for (int l = 0; l < NL; ++l) {
        vals[l] = (l < nn) ? tbl[(size_t)idxv[l] * NE + lane] : 0.0f;
    }

    float acc = 0.0f;
#pragma unroll
    for (int l = 0; l < NL; ++l) {
        acc += w[l] * vals[l];
    }

    // pred[b, f*E + e] — block writes a contiguous 1 KiB region.
    pred[((size_t)b * NF + f) * NE + lane] = acc;

    // --- deterministic block partial sum for the loss ---
    float s = acc;
#pragma unroll
    for (int off = 32; off > 0; off >>= 1)
        s += __shfl_down(s, off, 64);

    __shared__ float wsum[4];
    if (lane == 0) wsum[f] = s;
    __syncthreads();
    if (tid == 0)
        partial[b] = (wsum[0] + wsum[1]) + (wsum[2] + wsum[3]);
}

// Single-block deterministic reduce of the 16384 block partials -> loss.
__global__ __launch_bounds__(256) void loss_kernel(
    const float* __restrict__ partial,
    float*       __restrict__ loss_out)
{
    const int tid  = threadIdx.x;
    const int lane = tid & 63;
    const int wv   = tid >> 6;

    float s = 0.0f;
    for (int i = tid; i < NB; i += 256)
        s += partial[i];

#pragma unroll
    for (int off = 32; off > 0; off >>= 1)
        s += __shfl_down(s, off, 64);

    __shared__ float wsum[4];
    if (lane == 0) wsum[wv] = s;
    __syncthreads();
    if (tid == 0) {
        const double denom = (double)NB * (double)NF * (double)NE;
        loss_out[0] = (float)(((double)wsum[0] + wsum[1] + wsum[2] + wsum[3]) / denom);
    }
}

extern "C" void kernel_launch(void* const* d_in, const int* in_sizes, int n_in,
                              void* d_out, int out_size, void* d_ws, size_t ws_size,
                              hipStream_t stream) {
    const float* tables      = (const float*)d_in[0];
    const float* pos_weights = (const float*)d_in[1];
    const int*   indices     = (const int*)d_in[2];
    const int*   lengths     = (const int*)d_in[3];

    float* out  = (float*)d_out;            // out[0] = loss, out[1..] = pred [B, F*E]
    float* pred = out + 1;
    float* partial = (float*)d_ws;          // NB floats = 64 KiB

    bag_kernel<<<NB, 256, 0, stream>>>(tables, pos_weights, indices, lengths, pred, partial);
    loss_kernel<<<1, 256, 0, stream>>>(partial, out);
}